// Round 13
// baseline (138.697 us; speedup 1.0000x reference)
//
#include <hip/hip_runtime.h>

#define NJ 24
#define NF 7
#define FS 6
#define THREADS 256
#define CUNITS 12   // float4 per thread per chunk (4 joint-pairs = 192 B)
#define PAD 13      // LDS stride in float4 units
#define KGROUPS 4   // sample-groups per block (persistent depth)

typedef float v4f __attribute__((ext_vector_type(4)));

// parent of each joint; parents[i] < i, so sequential order is topological
__device__ constexpr int kParents[NJ] = {-1, 0, 0, 0, 1, 2, 3, 4, 5, 6, 7, 8,
                                          9, 9, 9, 12, 13, 14, 16, 17, 18, 19, 20, 21};

// Compute joint i; stage completed joint-pairs (3 x v4f) into wave-private LDS.
#define JOINT(i)                                                              \
    {                                                                         \
        const int p_ = kParents[i];                                           \
        float inp_[NF];                                                       \
        inp_[0] = xr[i];                                                      \
        _Pragma("unroll")                                                     \
        for (int j = 0; j < FS; ++j)                                          \
            inp_[1 + j] = (p_ < 0) ? 0.0f : feats[(p_ < 0) ? 0 : p_][j];      \
        float h_[NF];                                                         \
        _Pragma("unroll")                                                     \
        for (int j = 0; j < NF; ++j) h_[j] = b1[(i) * NF + j];                \
        _Pragma("unroll")                                                     \
        for (int k = 0; k < NF; ++k) {                                        \
            const float a_ = inp_[k];                                         \
            _Pragma("unroll")                                                 \
            for (int j = 0; j < NF; ++j)                                      \
                h_[j] = fmaf(a_, W1[(i) * NF * NF + k * NF + j], h_[j]);      \
        }                                                                     \
        _Pragma("unroll")                                                     \
        for (int j = 0; j < NF; ++j) h_[j] = fmaxf(h_[j], 0.0f);              \
        float f_[FS];                                                         \
        _Pragma("unroll")                                                     \
        for (int j = 0; j < FS; ++j) f_[j] = b2[(i) * FS + j];                \
        _Pragma("unroll")                                                     \
        for (int k = 0; k < NF; ++k) {                                        \
            const float a_ = h_[k];                                           \
            _Pragma("unroll")                                                 \
            for (int j = 0; j < FS; ++j)                                      \
                f_[j] = fmaf(a_, W2[(i) * NF * FS + k * FS + j], f_[j]);      \
        }                                                                     \
        _Pragma("unroll")                                                     \
        for (int j = 0; j < FS; ++j) {                                        \
            f_[j] = fmaxf(f_[j], 0.0f);                                       \
            feats[i][j] = f_[j];                                              \
        }                                                                     \
        if ((i) & 1) {                                                        \
            const int pp_ = ((i) >> 1) & 3;                                   \
            v4f* st_ = myStage + pp_ * 3;                                     \
            st_[0] = (v4f){feats[(i) - 1][0], feats[(i) - 1][1],              \
                           feats[(i) - 1][2], feats[(i) - 1][3]};             \
            st_[1] = (v4f){feats[(i) - 1][4], feats[(i) - 1][5],              \
                           f_[0], f_[1]};                                     \
            st_[2] = (v4f){f_[2], f_[3], f_[4], f_[5]};                       \
        }                                                                     \
    }

// Burst flush: 12 ds_read_b128 into the persistent decoupled set fr[], then
// 12 fire-and-forget NT stores (SGPR base + 32b offset + imm). Each store =
// 16 complete 64B lines (proven R3).
#define FLUSH(CBYTES)                                                         \
    {                                                                         \
        _Pragma("unroll")                                                     \
        for (int j = 0; j < CUNITS; ++j) {                                    \
            const int G = j * 64 + lane;                                      \
            const int s = G / CUNITS;                                         \
            const int q = G - s * CUNITS;                                     \
            fr[j] = sm[wid][s * PAD + q];                                     \
        }                                                                     \
        _Pragma("unroll")                                                     \
        for (int j = 0; j < CUNITS; ++j) {                                    \
            v4f* dst_ = reinterpret_cast<v4f*>(obase + voff[j] + (CBYTES));   \
            __builtin_nontemporal_store(fr[j], dst_);                         \
        }                                                                     \
    }

#define KEEP12(A)                                                             \
    asm volatile("" :: "v"(A[0]), "v"(A[1]), "v"(A[2]), "v"(A[3]),            \
                 "v"(A[4]), "v"(A[5]), "v"(A[6]), "v"(A[7]),                  \
                 "v"(A[8]), "v"(A[9]), "v"(A[10]), "v"(A[11]));

// Unpack 6 prefetched v4f into the group's xr[24] scalars.
#define UNPACK_X()                                                            \
    {                                                                         \
        _Pragma("unroll")                                                     \
        for (int c = 0; c < 6; ++c) {                                         \
            xr[c * 4 + 0] = xp[c].x; xr[c * 4 + 1] = xp[c].y;                 \
            xr[c * 4 + 2] = xp[c].z; xr[c * 4 + 3] = xp[c].w;                 \
        }                                                                     \
    }

// Requires B % (THREADS*KGROUPS) == 0 (bench: B = 524288 = 512*1024).
__global__ __launch_bounds__(THREADS, 2) void se1d_kernel(
    const float* __restrict__ x,
    const float* __restrict__ W1,
    const float* __restrict__ b1,
    const float* __restrict__ W2,
    const float* __restrict__ b2,
    float* __restrict__ out, int B)
{
    // Wave-private staging (no barriers; per-wave DS pipe is in-order).
    __shared__ v4f sm[THREADS / 64][64 * PAD];

    const int t    = threadIdx.x;
    const int lane = t & 63;
    const int wid  = __builtin_amdgcn_readfirstlane(threadIdx.x >> 6);
    const int b0   = blockIdx.x * (THREADS * KGROUPS) + t;        // group-0 sample
    const int wb0  = blockIdx.x * (THREADS * KGROUPS) + wid * 64; // group-0 wave base

    v4f* const myStage = &sm[wid][lane * PAD];

    // Per-lane store byte-offsets within a wave's 36 KB output region
    // (identical for every chunk/group; chunk & group go into base/imm).
    int voff[CUNITS];
    #pragma unroll
    for (int j = 0; j < CUNITS; ++j) {
        const int G = j * 64 + lane;
        const int s = G / CUNITS;
        const int q = G - s * CUNITS;
        voff[j] = (s * 36 + q) * 16;   // bytes
    }

    const float* xptr = x + (size_t)b0 * NJ;       // this thread's x row
    char* obase = reinterpret_cast<char*>(reinterpret_cast<v4f*>(out) +
                                          (size_t)wb0 * 36);

    float feats[NJ][FS];  // fully unrolled -> registers, ~3 joints live
    float xr[NJ];
    v4f xp[6];            // prefetched next-group x (held across flushes)
    v4f fr[CUNITS];       // persistent decoupled store-data set (pinned)

    // Prime: group 0's x.
    {
        const v4f* xv = reinterpret_cast<const v4f*>(xptr);
        #pragma unroll
        for (int c = 0; c < 6; ++c) xp[c] = __builtin_nontemporal_load(xv + c);
    }

    #pragma unroll 1
    for (int g = 0; g < KGROUPS; ++g) {
        UNPACK_X();
        // Prefetch next group's x BEFORE this group's stores are issued:
        // vmcnt is in-order, so xr's consume-wait (vmcnt(12)) never drains
        // the younger store queue.
        if (g + 1 < KGROUPS) {
            const v4f* xv = reinterpret_cast<const v4f*>(
                xptr + (size_t)(g + 1) * THREADS * NJ);
            #pragma unroll
            for (int c = 0; c < 6; ++c)
                xp[c] = __builtin_nontemporal_load(xv + c);
        }

        JOINT(0) JOINT(1) JOINT(2) JOINT(3) JOINT(4) JOINT(5) JOINT(6) JOINT(7)
        FLUSH(0);
        JOINT(8) JOINT(9) JOINT(10) JOINT(11)
        JOINT(12) JOINT(13) JOINT(14) JOINT(15)
        FLUSH(192);
        JOINT(16) JOINT(17) JOINT(18) JOINT(19)
        JOINT(20) JOINT(21) JOINT(22) JOINT(23)
        FLUSH(384);

        obase += (size_t)THREADS * 36 * 16;   // advance one group (256 rows)
    }

    KEEP12(fr);
    (void)B;
}

extern "C" void kernel_launch(void* const* d_in, const int* in_sizes, int n_in,
                              void* d_out, int out_size, void* d_ws, size_t ws_size,
                              hipStream_t stream) {
    const float* x  = (const float*)d_in[0];
    const float* W1 = (const float*)d_in[1];
    const float* b1 = (const float*)d_in[2];
    const float* W2 = (const float*)d_in[3];
    const float* b2 = (const float*)d_in[4];
    float* out = (float*)d_out;
    const int B = in_sizes[0] / NJ;   // 524288
    const int grid = B / (THREADS * KGROUPS);   // 512
    hipLaunchKernelGGL(se1d_kernel, dim3(grid), dim3(THREADS), 0, stream,
                       x, W1, b1, W2, b2, out, B);
}

// Round 14
// 108.307 us; speedup vs baseline: 1.2806x; 1.2806x over previous
//
#include <hip/hip_runtime.h>

#define NJ 24
#define NF 7
#define FS 6
#define SROW 37   // staging row stride in v4f units (36 data + 1 pad)

typedef float v4f __attribute__((ext_vector_type(4)));

// parent of each joint; parents[i] < i, so sequential order is topological
__device__ constexpr int kParents[NJ] = {-1, 0, 0, 0, 1, 2, 3, 4, 5, 6, 7, 8,
                                          9, 9, 9, 12, 13, 14, 16, 17, 18, 19, 20, 21};

// Compute joint i; stage completed joint-pairs (3 x v4f) into this sample's
// full LDS row (row layout == output row layout: 36 v4f = 576 B).
#define JOINT(i)                                                              \
    {                                                                         \
        const int p_ = kParents[i];                                           \
        float inp_[NF];                                                       \
        inp_[0] = xr[i];                                                      \
        _Pragma("unroll")                                                     \
        for (int j = 0; j < FS; ++j)                                          \
            inp_[1 + j] = (p_ < 0) ? 0.0f : feats[(p_ < 0) ? 0 : p_][j];      \
        float h_[NF];                                                         \
        _Pragma("unroll")                                                     \
        for (int j = 0; j < NF; ++j) h_[j] = b1[(i) * NF + j];                \
        _Pragma("unroll")                                                     \
        for (int k = 0; k < NF; ++k) {                                        \
            const float a_ = inp_[k];                                         \
            _Pragma("unroll")                                                 \
            for (int j = 0; j < NF; ++j)                                      \
                h_[j] = fmaf(a_, W1[(i) * NF * NF + k * NF + j], h_[j]);      \
        }                                                                     \
        _Pragma("unroll")                                                     \
        for (int j = 0; j < NF; ++j) h_[j] = fmaxf(h_[j], 0.0f);              \
        float f_[FS];                                                         \
        _Pragma("unroll")                                                     \
        for (int j = 0; j < FS; ++j) f_[j] = b2[(i) * FS + j];                \
        _Pragma("unroll")                                                     \
        for (int k = 0; k < NF; ++k) {                                        \
            const float a_ = h_[k];                                           \
            _Pragma("unroll")                                                 \
            for (int j = 0; j < FS; ++j)                                      \
                f_[j] = fmaf(a_, W2[(i) * NF * FS + k * FS + j], f_[j]);      \
        }                                                                     \
        _Pragma("unroll")                                                     \
        for (int j = 0; j < FS; ++j) {                                        \
            f_[j] = fmaxf(f_[j], 0.0f);                                       \
            feats[i][j] = f_[j];                                              \
        }                                                                     \
        if ((i) & 1) {                                                        \
            const int pp_ = (i) >> 1;          /* 0..11 */                    \
            v4f* st_ = myStage + pp_ * 3;                                     \
            st_[0] = (v4f){feats[(i) - 1][0], feats[(i) - 1][1],              \
                           feats[(i) - 1][2], feats[(i) - 1][3]};             \
            st_[1] = (v4f){feats[(i) - 1][4], feats[(i) - 1][5],              \
                           f_[0], f_[1]};                                     \
            st_[2] = (v4f){f_[2], f_[3], f_[4], f_[5]};                       \
        }                                                                     \
    }

// One sequential 12KB pass of the mega-flush: 12 ds_read_b128 into the
// decoupled set FR, then 12 contiguous 1KB wave-stores at outv[G],
// G = P*768 + j*64 + lane. Passes back-to-back sweep the block's 36KB
// output region in strictly ascending address order (the fill kernel's
// pattern, which sustains 6.9 TB/s).
#define PASS(P, FR)                                                           \
    {                                                                         \
        _Pragma("unroll")                                                     \
        for (int j = 0; j < 12; ++j) {                                        \
            const int G = (P) * 768 + j * 64 + lane;                          \
            const int s = G / 36;                                             \
            const int q = G - s * 36;                                         \
            FR[j] = sm[s * SROW + q];                                         \
        }                                                                     \
        _Pragma("unroll")                                                     \
        for (int j = 0; j < 12; ++j)                                          \
            __builtin_nontemporal_store(FR[j],                                \
                                        outv + (P) * 768 + j * 64 + lane);    \
    }

#define KEEP12(A)                                                             \
    asm volatile("" :: "v"(A[0]), "v"(A[1]), "v"(A[2]), "v"(A[3]),            \
                 "v"(A[4]), "v"(A[5]), "v"(A[6]), "v"(A[7]),                  \
                 "v"(A[8]), "v"(A[9]), "v"(A[10]), "v"(A[11]));

// Requires B % 64 == 0 (bench: B = 524288 -> grid 8192).
// 1 wave/block, 37.9 KB LDS -> 4 blocks/CU (one wave per SIMD); compute
// serialization across rounds (~18 us/CU) is far below the ~55 us write
// floor, and cross-SIMD stagger keeps the store path continuously fed.
__global__ __launch_bounds__(64) void se1d_kernel(
    const float* __restrict__ x,
    const float* __restrict__ W1,
    const float* __restrict__ b1,
    const float* __restrict__ W2,
    const float* __restrict__ b2,
    float* __restrict__ out, int B)
{
    __shared__ v4f sm[64 * SROW];   // 37888 B: full 576B rows for 64 samples

    const int lane = threadIdx.x;        // 0..63 (one wave)
    const int base = blockIdx.x * 64;    // this block's 64 samples
    const int b    = base + lane;

    v4f* const myStage = &sm[lane * SROW];
    v4f* const outv = reinterpret_cast<v4f*>(out) + (size_t)base * 36;

    // 24 x-values, NT (read-once stream), 96 B contiguous.
    float xr[NJ];
    {
        const v4f* xv = reinterpret_cast<const v4f*>(x + (size_t)b * NJ);
        #pragma unroll
        for (int c = 0; c < NJ / 4; ++c) {
            v4f v = __builtin_nontemporal_load(xv + c);
            xr[c * 4 + 0] = v.x; xr[c * 4 + 1] = v.y;
            xr[c * 4 + 2] = v.z; xr[c * 4 + 3] = v.w;
        }
    }

    // Weights: compile-time-constant indices off uniform kernel args ->
    // s_load into SGPRs (L2/K$-resident 10 KB), v_fmac consumes SGPR operand.
    float feats[NJ][FS];  // fully unrolled -> registers, ~3 joints live

    JOINT(0)  JOINT(1)  JOINT(2)  JOINT(3)  JOINT(4)  JOINT(5)
    JOINT(6)  JOINT(7)  JOINT(8)  JOINT(9)  JOINT(10) JOINT(11)
    JOINT(12) JOINT(13) JOINT(14) JOINT(15) JOINT(16) JOINT(17)
    JOINT(18) JOINT(19) JOINT(20) JOINT(21) JOINT(22) JOINT(23)

    // Sequential mega-flush: 36 KB in ascending order, ping-pong decoupled
    // (pass 2 reuses fra only after 24 younger stores -> ample ack slack).
    v4f fra[12], frb[12];
    PASS(0, fra);
    PASS(1, frb);
    PASS(2, fra);

    KEEP12(fra);
    KEEP12(frb);
    (void)B;
}

extern "C" void kernel_launch(void* const* d_in, const int* in_sizes, int n_in,
                              void* d_out, int out_size, void* d_ws, size_t ws_size,
                              hipStream_t stream) {
    const float* x  = (const float*)d_in[0];
    const float* W1 = (const float*)d_in[1];
    const float* b1 = (const float*)d_in[2];
    const float* W2 = (const float*)d_in[3];
    const float* b2 = (const float*)d_in[4];
    float* out = (float*)d_out;
    const int B = in_sizes[0] / NJ;   // 524288, multiple of 64
    const int grid = B / 64;          // 8192
    hipLaunchKernelGGL(se1d_kernel, dim3(grid), dim3(64), 0, stream,
                       x, W1, b1, W2, b2, out, B);
}

// Round 15
// 102.305 us; speedup vs baseline: 1.3557x; 1.0587x over previous
//
#include <hip/hip_runtime.h>

#define NJ 24
#define NF 7
#define FS 6
#define THREADS 256
#define CUNITS 12   // float4 per thread per chunk (4 joint-pairs = 192 B)
#define PAD 13      // LDS stride in float4 units

typedef float v4f __attribute__((ext_vector_type(4)));

// parent of each joint; parents[i] < i, so sequential order is topological
__device__ constexpr int kParents[NJ] = {-1, 0, 0, 0, 1, 2, 3, 4, 5, 6, 7, 8,
                                          9, 9, 9, 12, 13, 14, 16, 17, 18, 19, 20, 21};

// Compute joint i; stage completed joint-pairs (3 x v4f) into wave-private LDS.
#define JOINT(i)                                                              \
    {                                                                         \
        const int p_ = kParents[i];                                           \
        float inp_[NF];                                                       \
        inp_[0] = xr[i];                                                      \
        _Pragma("unroll")                                                     \
        for (int j = 0; j < FS; ++j)                                          \
            inp_[1 + j] = (p_ < 0) ? 0.0f : feats[(p_ < 0) ? 0 : p_][j];      \
        float h_[NF];                                                         \
        _Pragma("unroll")                                                     \
        for (int j = 0; j < NF; ++j) h_[j] = b1[(i) * NF + j];                \
        _Pragma("unroll")                                                     \
        for (int k = 0; k < NF; ++k) {                                        \
            const float a_ = inp_[k];                                         \
            _Pragma("unroll")                                                 \
            for (int j = 0; j < NF; ++j)                                      \
                h_[j] = fmaf(a_, W1[(i) * NF * NF + k * NF + j], h_[j]);      \
        }                                                                     \
        _Pragma("unroll")                                                     \
        for (int j = 0; j < NF; ++j) h_[j] = fmaxf(h_[j], 0.0f);              \
        float f_[FS];                                                         \
        _Pragma("unroll")                                                     \
        for (int j = 0; j < FS; ++j) f_[j] = b2[(i) * FS + j];                \
        _Pragma("unroll")                                                     \
        for (int k = 0; k < NF; ++k) {                                        \
            const float a_ = h_[k];                                           \
            _Pragma("unroll")                                                 \
            for (int j = 0; j < FS; ++j)                                      \
                f_[j] = fmaf(a_, W2[(i) * NF * FS + k * FS + j], f_[j]);      \
        }                                                                     \
        _Pragma("unroll")                                                     \
        for (int j = 0; j < FS; ++j) {                                        \
            f_[j] = fmaxf(f_[j], 0.0f);                                       \
            feats[i][j] = f_[j];                                              \
        }                                                                     \
        if ((i) & 1) {                                                        \
            const int pp_ = ((i) >> 1) & 3;                                   \
            v4f* st_ = myStage + pp_ * 3;                                     \
            st_[0] = (v4f){feats[(i) - 1][0], feats[(i) - 1][1],              \
                           feats[(i) - 1][2], feats[(i) - 1][3]};             \
            st_[1] = (v4f){feats[(i) - 1][4], feats[(i) - 1][5],              \
                           f_[0], f_[1]};                                     \
            st_[2] = (v4f){f_[2], f_[3], f_[4], f_[5]};                       \
        }                                                                     \
    }

// Flush chunk C: 12 ds_read_b128 into the persistent decoupled set fr[],
// then 12 PLAIN stores (L2 write-back path -- the fill kernel's 6.9 TB/s
// path; L2 absorbs the burst at ~200cyc ack and streams evictions to HBM).
// SGPR base + 32b VGPR offset + chunk imm. Each store = 16 full 64B lines.
#define FLUSH(C)                                                              \
    {                                                                         \
        _Pragma("unroll")                                                     \
        for (int j = 0; j < CUNITS; ++j) {                                    \
            const int G = j * 64 + lane;                                      \
            const int s = G / CUNITS;                                         \
            const int q = G - s * CUNITS;                                     \
            fr[j] = sm[wid][s * PAD + q];                                     \
        }                                                                     \
        _Pragma("unroll")                                                     \
        for (int j = 0; j < CUNITS; ++j) {                                    \
            v4f* dst_ = reinterpret_cast<v4f*>(                               \
                reinterpret_cast<char*>(obase) + voff[j] + (C) * 192);        \
            *dst_ = fr[j];                                                    \
        }                                                                     \
    }

// Pin the persistent store-data set to kernel end (keeps the allocator from
// recycling a pending store's source reg into compute temps).
#define KEEP12(A)                                                             \
    asm volatile("" :: "v"(A[0]), "v"(A[1]), "v"(A[2]), "v"(A[3]),            \
                 "v"(A[4]), "v"(A[5]), "v"(A[6]), "v"(A[7]),                  \
                 "v"(A[8]), "v"(A[9]), "v"(A[10]), "v"(A[11]));

// Requires B % 256 == 0 (bench: B = 524288).
__global__ __launch_bounds__(THREADS, 3) void se1d_kernel(
    const float* __restrict__ x,
    const float* __restrict__ W1,
    const float* __restrict__ b1,
    const float* __restrict__ W2,
    const float* __restrict__ b2,
    float* __restrict__ out, int B)
{
    // Wave-private staging: 64 lanes x 13 v4f = 13312 B/wave, 53 KB/block
    // -> 3 blocks/CU (12 waves). No barriers (wave-synchronous; per-wave DS
    // pipe is in-order).
    __shared__ v4f sm[THREADS / 64][64 * PAD];

    const int t    = threadIdx.x;
    const int lane = t & 63;
    const int wid  = __builtin_amdgcn_readfirstlane(threadIdx.x >> 6);
    const int b    = blockIdx.x * THREADS + t;         // this thread's sample
    const int wb   = blockIdx.x * THREADS + wid * 64;  // wave base (uniform)

    v4f* const myStage = &sm[wid][lane * PAD];
    v4f* const obase = reinterpret_cast<v4f*>(out) + (size_t)wb * 36;

    // Per-lane store byte-offsets within the wave's 36 KB output region.
    int voff[CUNITS];
    #pragma unroll
    for (int j = 0; j < CUNITS; ++j) {
        const int G = j * 64 + lane;
        const int s = G / CUNITS;
        const int q = G - s * CUNITS;
        voff[j] = (s * 36 + q) * 16;   // bytes
    }

    // ALL x loaded up-front, non-temporal (read-once stream; keeps x out of
    // L2 so the write stream has the full cache).
    float xr[NJ];
    {
        const v4f* xv = reinterpret_cast<const v4f*>(x + (size_t)b * NJ);
        #pragma unroll
        for (int c = 0; c < NJ / 4; ++c) {
            v4f v = __builtin_nontemporal_load(xv + c);
            xr[c * 4 + 0] = v.x; xr[c * 4 + 1] = v.y;
            xr[c * 4 + 2] = v.z; xr[c * 4 + 3] = v.w;
        }
    }

    float feats[NJ][FS];  // fully unrolled -> registers, ~3 joints live
    v4f fr[CUNITS];       // persistent decoupled store-data set (pinned)

    // chunk 0
    JOINT(0) JOINT(1) JOINT(2) JOINT(3) JOINT(4) JOINT(5) JOINT(6) JOINT(7)
    FLUSH(0);
    // chunk 1 (fr overwrite waits only on chunk-0's oldest store ack)
    JOINT(8) JOINT(9) JOINT(10) JOINT(11)
    JOINT(12) JOINT(13) JOINT(14) JOINT(15)
    FLUSH(1);
    // chunk 2
    JOINT(16) JOINT(17) JOINT(18) JOINT(19)
    JOINT(20) JOINT(21) JOINT(22) JOINT(23)
    FLUSH(2);

    KEEP12(fr);
    (void)B;
}

extern "C" void kernel_launch(void* const* d_in, const int* in_sizes, int n_in,
                              void* d_out, int out_size, void* d_ws, size_t ws_size,
                              hipStream_t stream) {
    const float* x  = (const float*)d_in[0];
    const float* W1 = (const float*)d_in[1];
    const float* b1 = (const float*)d_in[2];
    const float* W2 = (const float*)d_in[3];
    const float* b2 = (const float*)d_in[4];
    float* out = (float*)d_out;
    const int B = in_sizes[0] / NJ;   // 524288, multiple of 256
    const int grid = B / THREADS;
    hipLaunchKernelGGL(se1d_kernel, dim3(grid), dim3(THREADS), 0, stream,
                       x, W1, b1, W2, b2, out, B);
}